// Round 2
// baseline (305.781 us; speedup 1.0000x reference)
//
#include <hip/hip_runtime.h>
#include <math.h>

#define N_NODES 50000
#define N_EDGES 800000
#define IN_F 256
#define OUT_F 64
#define ALPHA 0.2f

// K1: Wh = leaky_relu(h @ W); e2 = Wh @ a[64:128]
// block = 256 threads, 64 rows/block, k-tiled (KT=64), 4 rows x 4 cols per thread
__global__ __launch_bounds__(256) void k1_gemm(
    const float* __restrict__ h, const float* __restrict__ W,
    const float* __restrict__ a, float* __restrict__ Wh,
    float* __restrict__ e2out) {
    __shared__ float hs[64 * 68];   // stride 68 to break bank conflicts
    __shared__ float wsm[64 * 64];

    const int tid = threadIdx.x;
    const int row0 = blockIdx.x * 64;
    const int cg = tid & 15;   // col group: cols cg*4 .. cg*4+3
    const int rg = tid >> 4;   // row group: rows rg*4 .. rg*4+3

    float acc[4][4] = {};

    for (int k0 = 0; k0 < IN_F; k0 += 64) {
        __syncthreads();
#pragma unroll
        for (int j = 0; j < 4; ++j) {
            int q = tid + j * 256;          // 0..1023
            int r = q >> 4;
            int c4 = (q & 15) * 4;
            int row = row0 + r;
            float4 v = make_float4(0.f, 0.f, 0.f, 0.f);
            if (row < N_NODES)
                v = *(const float4*)&h[(size_t)row * IN_F + k0 + c4];
            *(float4*)&hs[r * 68 + c4] = v;
        }
#pragma unroll
        for (int j = 0; j < 4; ++j) {
            int q = tid + j * 256;
            int r = q >> 4;
            int c4 = (q & 15) * 4;
            *(float4*)&wsm[r * 64 + c4] =
                *(const float4*)&W[(size_t)(k0 + r) * OUT_F + c4];
        }
        __syncthreads();

        for (int kk = 0; kk < 64; ++kk) {
            float4 wv = *(const float4*)&wsm[kk * 64 + cg * 4];
#pragma unroll
            for (int i = 0; i < 4; ++i) {
                float hv = hs[(rg * 4 + i) * 68 + kk];
                acc[i][0] += hv * wv.x;
                acc[i][1] += hv * wv.y;
                acc[i][2] += hv * wv.z;
                acc[i][3] += hv * wv.w;
            }
        }
    }

    float a2[4];
#pragma unroll
    for (int j = 0; j < 4; ++j) a2[j] = a[OUT_F + cg * 4 + j];

#pragma unroll
    for (int i = 0; i < 4; ++i) {
        int row = row0 + rg * 4 + i;
        float4 lr;
        float p2 = 0.f;
        {
            float v;
            v = acc[i][0]; v = v > 0.f ? v : ALPHA * v; lr.x = v; p2 += v * a2[0];
            v = acc[i][1]; v = v > 0.f ? v : ALPHA * v; lr.y = v; p2 += v * a2[1];
            v = acc[i][2]; v = v > 0.f ? v : ALPHA * v; lr.z = v; p2 += v * a2[2];
            v = acc[i][3]; v = v > 0.f ? v : ALPHA * v; lr.w = v; p2 += v * a2[3];
        }
        if (row < N_NODES)
            *(float4*)&Wh[(size_t)row * OUT_F + cg * 4] = lr;
        // reduce p2 across the 16 col-group lanes
#pragma unroll
        for (int mask = 1; mask < 16; mask <<= 1)
            p2 += __shfl_xor(p2, mask, 64);
        if (cg == 0 && row < N_NODES) e2out[row] = p2;
    }
}

// K2: histogram of src
__global__ __launch_bounds__(256) void k_hist(
    const int* __restrict__ ei, int* __restrict__ counts) {
    int e = blockIdx.x * blockDim.x + threadIdx.x;
    if (e >= N_EDGES) return;
    atomicAdd(counts + ei[e], 1);
}

// K3: single-block exclusive scan of counts -> off (off[N_NODES] = N_EDGES)
__global__ __launch_bounds__(1024) void k_scan(
    const int* __restrict__ counts, int* __restrict__ off) {
    __shared__ int sums[1024];
    const int t = threadIdx.x;
    const int CH = (N_NODES + 1023) / 1024;  // 49
    const int base = t * CH;
    int s = 0;
    for (int i = 0; i < CH; ++i) {
        int idx = base + i;
        if (idx < N_NODES) s += counts[idx];
    }
    sums[t] = s;
    __syncthreads();
    // inclusive Hillis-Steele scan over 1024 partials
    for (int o = 1; o < 1024; o <<= 1) {
        int v = (t >= o) ? sums[t - o] : 0;
        __syncthreads();
        sums[t] += v;
        __syncthreads();
    }
    int run = sums[t] - s;  // exclusive prefix for this chunk
    for (int i = 0; i < CH; ++i) {
        int idx = base + i;
        if (idx < N_NODES) {
            off[idx] = run;
            run += counts[idx];
        }
    }
    if (t == 0) off[N_NODES] = N_EDGES;
}

// K4: scatter edges into CSR order; pre-gather e2[dst]
__global__ __launch_bounds__(256) void k_scatter(
    const int* __restrict__ ei, const float* __restrict__ e2,
    const int* __restrict__ off, int* __restrict__ cursor,
    int* __restrict__ sd, float* __restrict__ e2s) {
    int e = blockIdx.x * blockDim.x + threadIdx.x;
    if (e >= N_EDGES) return;
    int s = ei[e];
    int d = ei[N_EDGES + e];
    int pos = off[s] + atomicAdd(cursor + s, 1);
    sd[pos] = d;
    e2s[pos] = e2[d];
}

// K5: one wave per node; lane = feature. Two-pass softmax + aggregate + ELU.
__global__ __launch_bounds__(256) void k_agg(
    const int* __restrict__ off, const int* __restrict__ sd,
    const float* __restrict__ e2s, const float* __restrict__ Wh,
    float* __restrict__ out) {
    const int lane = threadIdx.x & 63;
    const int node = (blockIdx.x * blockDim.x + threadIdx.x) >> 6;
    if (node >= N_NODES) return;
    const int start = off[node];
    const int end = off[node + 1];

    // pass 1: segment max (lane-strided over linear e2s)
    float m = -1e30f;
    for (int j = start + lane; j < end; j += 64) m = fmaxf(m, e2s[j]);
#pragma unroll
    for (int mask = 32; mask; mask >>= 1)
        m = fmaxf(m, __shfl_xor(m, mask, 64));

    // pass 2: serial over segment, coalesced Wh row reads
    float acc = 0.f, den = 0.f;
    for (int j = start; j < end; ++j) {
        int d = sd[j];
        float ee = __expf(e2s[j] - m);
        den += ee;
        acc += ee * Wh[(size_t)d * OUT_F + lane];
    }
    float v = (end > start) ? acc / den : 0.f;
    out[(size_t)node * OUT_F + lane] = v > 0.f ? v : expm1f(v);
}

extern "C" void kernel_launch(void* const* d_in, const int* in_sizes, int n_in,
                              void* d_out, int out_size, void* d_ws,
                              size_t ws_size, hipStream_t stream) {
    const float* h = (const float*)d_in[0];
    const int* ei = (const int*)d_in[1];
    const float* W = (const float*)d_in[2];
    const float* a = (const float*)d_in[3];
    float* out = (float*)d_out;

    float* ws = (float*)d_ws;
    float* Wh = ws;                                 // 3,200,000 floats
    float* e2 = ws + 3200000;                       // 50,000
    int* counts = (int*)(ws + 3250000);             // 50,000
    int* cursor = (int*)(ws + 3300000);             // 50,000
    int* off = (int*)(ws + 3350000);                // 50,001
    int* sd = (int*)(ws + 3410000);                 // 800,000
    float* e2s = ws + 4210000;                      // 800,000
    // total 5,010,000 floats ≈ 20 MB

    // zero counts + cursor (contiguous)
    hipMemsetAsync(counts, 0, (size_t)100000 * 4, stream);

    k1_gemm<<<(N_NODES + 63) / 64, 256, 0, stream>>>(h, W, a, Wh, e2);
    k_hist<<<(N_EDGES + 255) / 256, 256, 0, stream>>>(ei, counts);
    k_scan<<<1, 1024, 0, stream>>>(counts, off);
    k_scatter<<<(N_EDGES + 255) / 256, 256, 0, stream>>>(ei, e2, off, cursor,
                                                         sd, e2s);
    k_agg<<<(N_NODES * 64 + 255) / 256, 256, 0, stream>>>(off, sd, e2s, Wh,
                                                          out);
}

// Round 3
// 224.856 us; speedup vs baseline: 1.3599x; 1.3599x over previous
//
#include <hip/hip_runtime.h>
#include <math.h>

#define N_NODES 50000
#define N_EDGES 800000
#define IN_F 256
#define OUT_F 64
#define ALPHA 0.2f
#define SCAN_NB ((N_NODES + 255) / 256)   // 196

// K1: Wh = leaky_relu(h @ W); e2 = Wh @ a[64:128]
__global__ __launch_bounds__(256) void k1_gemm(
    const float* __restrict__ h, const float* __restrict__ W,
    const float* __restrict__ a, float* __restrict__ Wh,
    float* __restrict__ e2out) {
    __shared__ float hs[64 * 68];
    __shared__ float wsm[64 * 64];

    const int tid = threadIdx.x;
    const int row0 = blockIdx.x * 64;
    const int cg = tid & 15;
    const int rg = tid >> 4;

    float acc[4][4] = {};

    for (int k0 = 0; k0 < IN_F; k0 += 64) {
        __syncthreads();
#pragma unroll
        for (int j = 0; j < 4; ++j) {
            int q = tid + j * 256;
            int r = q >> 4;
            int c4 = (q & 15) * 4;
            int row = row0 + r;
            float4 v = make_float4(0.f, 0.f, 0.f, 0.f);
            if (row < N_NODES)
                v = *(const float4*)&h[(size_t)row * IN_F + k0 + c4];
            *(float4*)&hs[r * 68 + c4] = v;
        }
#pragma unroll
        for (int j = 0; j < 4; ++j) {
            int q = tid + j * 256;
            int r = q >> 4;
            int c4 = (q & 15) * 4;
            *(float4*)&wsm[r * 64 + c4] =
                *(const float4*)&W[(size_t)(k0 + r) * OUT_F + c4];
        }
        __syncthreads();

        for (int kk = 0; kk < 64; ++kk) {
            float4 wv = *(const float4*)&wsm[kk * 64 + cg * 4];
#pragma unroll
            for (int i = 0; i < 4; ++i) {
                float hv = hs[(rg * 4 + i) * 68 + kk];
                acc[i][0] += hv * wv.x;
                acc[i][1] += hv * wv.y;
                acc[i][2] += hv * wv.z;
                acc[i][3] += hv * wv.w;
            }
        }
    }

    float a2[4];
#pragma unroll
    for (int j = 0; j < 4; ++j) a2[j] = a[OUT_F + cg * 4 + j];

#pragma unroll
    for (int i = 0; i < 4; ++i) {
        int row = row0 + rg * 4 + i;
        float4 lr;
        float p2 = 0.f;
        {
            float v;
            v = acc[i][0]; v = v > 0.f ? v : ALPHA * v; lr.x = v; p2 += v * a2[0];
            v = acc[i][1]; v = v > 0.f ? v : ALPHA * v; lr.y = v; p2 += v * a2[1];
            v = acc[i][2]; v = v > 0.f ? v : ALPHA * v; lr.z = v; p2 += v * a2[2];
            v = acc[i][3]; v = v > 0.f ? v : ALPHA * v; lr.w = v; p2 += v * a2[3];
        }
        if (row < N_NODES)
            *(float4*)&Wh[(size_t)row * OUT_F + cg * 4] = lr;
#pragma unroll
        for (int mask = 1; mask < 16; mask <<= 1)
            p2 += __shfl_xor(p2, mask, 64);
        if (cg == 0 && row < N_NODES) e2out[row] = p2;
    }
}

// K2: histogram of src
__global__ __launch_bounds__(256) void k_hist(
    const int* __restrict__ ei, int* __restrict__ counts) {
    int e = blockIdx.x * blockDim.x + threadIdx.x;
    if (e >= N_EDGES) return;
    atomicAdd(counts + ei[e], 1);
}

// scan phase 1: per-block (256 elems) sum -> bsum[b]
__global__ __launch_bounds__(256) void k_scan1(
    const int* __restrict__ counts, int* __restrict__ bsum) {
    __shared__ int ls[4];
    int i = blockIdx.x * 256 + threadIdx.x;
    int v = (i < N_NODES) ? counts[i] : 0;
#pragma unroll
    for (int m = 1; m < 64; m <<= 1) v += __shfl_xor(v, m, 64);
    if ((threadIdx.x & 63) == 0) ls[threadIdx.x >> 6] = v;
    __syncthreads();
    if (threadIdx.x == 0) bsum[blockIdx.x] = ls[0] + ls[1] + ls[2] + ls[3];
}

// scan phase 2: single block, exclusive scan of SCAN_NB block sums (in place)
__global__ __launch_bounds__(256) void k_scan2(int* __restrict__ bsum) {
    __shared__ int s[256];
    int t = threadIdx.x;
    int v = (t < SCAN_NB) ? bsum[t] : 0;
    s[t] = v;
    __syncthreads();
    for (int o = 1; o < 256; o <<= 1) {
        int u = (t >= o) ? s[t - o] : 0;
        __syncthreads();
        s[t] += u;
        __syncthreads();
    }
    if (t < SCAN_NB) bsum[t] = s[t] - v;  // exclusive
}

// scan phase 3: per-block exclusive scan + block offset -> off
__global__ __launch_bounds__(256) void k_scan3(
    const int* __restrict__ counts, const int* __restrict__ bsum,
    int* __restrict__ off) {
    __shared__ int s[256];
    int t = threadIdx.x;
    int i = blockIdx.x * 256 + t;
    int v = (i < N_NODES) ? counts[i] : 0;
    s[t] = v;
    __syncthreads();
    for (int o = 1; o < 256; o <<= 1) {
        int u = (t >= o) ? s[t - o] : 0;
        __syncthreads();
        s[t] += u;
        __syncthreads();
    }
    if (i < N_NODES) off[i] = bsum[blockIdx.x] + s[t] - v;
    if (i == 0) off[N_NODES] = N_EDGES;
}

// K4: scatter edges into CSR order; pre-gather e2[dst]
__global__ __launch_bounds__(256) void k_scatter(
    const int* __restrict__ ei, const float* __restrict__ e2,
    const int* __restrict__ off, int* __restrict__ cursor,
    int* __restrict__ sd, float* __restrict__ e2s) {
    int e = blockIdx.x * blockDim.x + threadIdx.x;
    if (e >= N_EDGES) return;
    int s = ei[e];
    int d = ei[N_EDGES + e];
    int pos = off[s] + atomicAdd(cursor + s, 1);
    sd[pos] = d;
    e2s[pos] = e2[d];
}

// K5: one wave per node; lane = feature. Two-pass softmax + aggregate + ELU.
__global__ __launch_bounds__(256) void k_agg(
    const int* __restrict__ off, const int* __restrict__ sd,
    const float* __restrict__ e2s, const float* __restrict__ Wh,
    float* __restrict__ out) {
    const int lane = threadIdx.x & 63;
    const int node = (blockIdx.x * blockDim.x + threadIdx.x) >> 6;
    if (node >= N_NODES) return;
    const int start = off[node];
    const int end = off[node + 1];

    float m = -1e30f;
    for (int j = start + lane; j < end; j += 64) m = fmaxf(m, e2s[j]);
#pragma unroll
    for (int mask = 32; mask; mask >>= 1)
        m = fmaxf(m, __shfl_xor(m, mask, 64));

    float acc = 0.f, den = 0.f;
    for (int j = start; j < end; ++j) {
        int d = sd[j];
        float ee = __expf(e2s[j] - m);
        den += ee;
        acc += ee * Wh[(size_t)d * OUT_F + lane];
    }
    float v = (end > start) ? acc / den : 0.f;
    out[(size_t)node * OUT_F + lane] = v > 0.f ? v : expm1f(v);
}

extern "C" void kernel_launch(void* const* d_in, const int* in_sizes, int n_in,
                              void* d_out, int out_size, void* d_ws,
                              size_t ws_size, hipStream_t stream) {
    const float* h = (const float*)d_in[0];
    const int* ei = (const int*)d_in[1];
    const float* W = (const float*)d_in[2];
    const float* a = (const float*)d_in[3];
    float* out = (float*)d_out;

    float* ws = (float*)d_ws;
    float* Wh = ws;                                 // 3,200,000 floats
    float* e2 = ws + 3200000;                       // 50,000
    int* counts = (int*)(ws + 3250000);             // 50,000
    int* cursor = (int*)(ws + 3300000);             // 50,000
    int* off = (int*)(ws + 3350000);                // 50,001
    int* sd = (int*)(ws + 3410000);                 // 800,000
    float* e2s = ws + 4210000;                      // 800,000
    int* bsum = (int*)(ws + 5010000);               // 196

    // zero counts + cursor (contiguous)
    hipMemsetAsync(counts, 0, (size_t)100000 * 4, stream);

    k1_gemm<<<(N_NODES + 63) / 64, 256, 0, stream>>>(h, W, a, Wh, e2);
    k_hist<<<(N_EDGES + 255) / 256, 256, 0, stream>>>(ei, counts);
    k_scan1<<<SCAN_NB, 256, 0, stream>>>(counts, bsum);
    k_scan2<<<1, 256, 0, stream>>>(bsum);
    k_scan3<<<SCAN_NB, 256, 0, stream>>>(counts, bsum, off);
    k_scatter<<<(N_EDGES + 255) / 256, 256, 0, stream>>>(ei, e2, off, cursor,
                                                         sd, e2s);
    k_agg<<<(N_NODES * 64 + 255) / 256, 256, 0, stream>>>(off, sd, e2s, Wh,
                                                          out);
}

// Round 4
// 165.548 us; speedup vs baseline: 1.8471x; 1.3582x over previous
//
#include <hip/hip_runtime.h>
#include <math.h>

#define N_NODES 50000
#define N_EDGES 800000
#define IN_F 256
#define OUT_F 64
#define ALPHA 0.2f
#define SCAN_NB ((N_NODES + 255) / 256)   // 196

// K1: Wh = leaky_relu(h @ W); e2 = Wh @ a[64:128]
__global__ __launch_bounds__(256) void k1_gemm(
    const float* __restrict__ h, const float* __restrict__ W,
    const float* __restrict__ a, float* __restrict__ Wh,
    float* __restrict__ e2out) {
    __shared__ float hs[64 * 68];
    __shared__ float wsm[64 * 64];

    const int tid = threadIdx.x;
    const int row0 = blockIdx.x * 64;
    const int cg = tid & 15;
    const int rg = tid >> 4;

    float acc[4][4] = {};

    for (int k0 = 0; k0 < IN_F; k0 += 64) {
        __syncthreads();
#pragma unroll
        for (int j = 0; j < 4; ++j) {
            int q = tid + j * 256;
            int r = q >> 4;
            int c4 = (q & 15) * 4;
            int row = row0 + r;
            float4 v = make_float4(0.f, 0.f, 0.f, 0.f);
            if (row < N_NODES)
                v = *(const float4*)&h[(size_t)row * IN_F + k0 + c4];
            *(float4*)&hs[r * 68 + c4] = v;
        }
#pragma unroll
        for (int j = 0; j < 4; ++j) {
            int q = tid + j * 256;
            int r = q >> 4;
            int c4 = (q & 15) * 4;
            *(float4*)&wsm[r * 64 + c4] =
                *(const float4*)&W[(size_t)(k0 + r) * OUT_F + c4];
        }
        __syncthreads();

        for (int kk = 0; kk < 64; ++kk) {
            float4 wv = *(const float4*)&wsm[kk * 64 + cg * 4];
#pragma unroll
            for (int i = 0; i < 4; ++i) {
                float hv = hs[(rg * 4 + i) * 68 + kk];
                acc[i][0] += hv * wv.x;
                acc[i][1] += hv * wv.y;
                acc[i][2] += hv * wv.z;
                acc[i][3] += hv * wv.w;
            }
        }
    }

    float a2[4];
#pragma unroll
    for (int j = 0; j < 4; ++j) a2[j] = a[OUT_F + cg * 4 + j];

#pragma unroll
    for (int i = 0; i < 4; ++i) {
        int row = row0 + rg * 4 + i;
        float4 lr;
        float p2 = 0.f;
        {
            float v;
            v = acc[i][0]; v = v > 0.f ? v : ALPHA * v; lr.x = v; p2 += v * a2[0];
            v = acc[i][1]; v = v > 0.f ? v : ALPHA * v; lr.y = v; p2 += v * a2[1];
            v = acc[i][2]; v = v > 0.f ? v : ALPHA * v; lr.z = v; p2 += v * a2[2];
            v = acc[i][3]; v = v > 0.f ? v : ALPHA * v; lr.w = v; p2 += v * a2[3];
        }
        if (row < N_NODES)
            *(float4*)&Wh[(size_t)row * OUT_F + cg * 4] = lr;
#pragma unroll
        for (int mask = 1; mask < 16; mask <<= 1)
            p2 += __shfl_xor(p2, mask, 64);
        if (cg == 0 && row < N_NODES) e2out[row] = p2;
    }
}

// K2: histogram of src
__global__ __launch_bounds__(256) void k_hist(
    const int* __restrict__ ei, int* __restrict__ counts) {
    int e = blockIdx.x * blockDim.x + threadIdx.x;
    if (e >= N_EDGES) return;
    atomicAdd(counts + ei[e], 1);
}

// scan phase 1: per-block (256 elems) sum -> bsum[b]
__global__ __launch_bounds__(256) void k_scan1(
    const int* __restrict__ counts, int* __restrict__ bsum) {
    __shared__ int ls[4];
    int i = blockIdx.x * 256 + threadIdx.x;
    int v = (i < N_NODES) ? counts[i] : 0;
#pragma unroll
    for (int m = 1; m < 64; m <<= 1) v += __shfl_xor(v, m, 64);
    if ((threadIdx.x & 63) == 0) ls[threadIdx.x >> 6] = v;
    __syncthreads();
    if (threadIdx.x == 0) bsum[blockIdx.x] = ls[0] + ls[1] + ls[2] + ls[3];
}

// scan phase 2: single block, exclusive scan of SCAN_NB block sums (in place)
__global__ __launch_bounds__(256) void k_scan2(int* __restrict__ bsum) {
    __shared__ int s[256];
    int t = threadIdx.x;
    int v = (t < SCAN_NB) ? bsum[t] : 0;
    s[t] = v;
    __syncthreads();
    for (int o = 1; o < 256; o <<= 1) {
        int u = (t >= o) ? s[t - o] : 0;
        __syncthreads();
        s[t] += u;
        __syncthreads();
    }
    if (t < SCAN_NB) bsum[t] = s[t] - v;  // exclusive
}

// scan phase 3: per-block exclusive scan + block offset -> off
__global__ __launch_bounds__(256) void k_scan3(
    const int* __restrict__ counts, const int* __restrict__ bsum,
    int* __restrict__ off) {
    __shared__ int s[256];
    int t = threadIdx.x;
    int i = blockIdx.x * 256 + t;
    int v = (i < N_NODES) ? counts[i] : 0;
    s[t] = v;
    __syncthreads();
    for (int o = 1; o < 256; o <<= 1) {
        int u = (t >= o) ? s[t - o] : 0;
        __syncthreads();
        s[t] += u;
        __syncthreads();
    }
    if (i < N_NODES) off[i] = bsum[blockIdx.x] + s[t] - v;
    if (i == 0) off[N_NODES] = N_EDGES;
}

// K4: scatter edges into CSR order; packed (dst, e2[dst]) per edge
__global__ __launch_bounds__(256) void k_scatter(
    const int* __restrict__ ei, const float* __restrict__ e2,
    const int* __restrict__ off, int* __restrict__ cursor,
    int2* __restrict__ edata) {
    int e = blockIdx.x * blockDim.x + threadIdx.x;
    if (e >= N_EDGES) return;
    int s = ei[e];
    int d = ei[N_EDGES + e];
    int pos = off[s] + atomicAdd(cursor + s, 1);
    edata[pos] = make_int2(d, __float_as_int(e2[d]));
}

// K5: one wave per node; 4 edge-slots x 16 feature-lanes.
__global__ __launch_bounds__(256) void k_agg(
    const int* __restrict__ off, const int2* __restrict__ edata,
    const float* __restrict__ Wh, float* __restrict__ out) {
    const int lane = threadIdx.x & 63;
    const int node = (blockIdx.x * blockDim.x + threadIdx.x) >> 6;
    if (node >= N_NODES) return;
    const int start = off[node];
    const int end = off[node + 1];
    const int slot = lane >> 4;   // 0..3: which edge in the group of 4
    const int fl = lane & 15;     // feature group: floats fl*4..fl*4+3

    // pass 1: segment max (lane-strided)
    float m = -1e30f;
    for (int j = start + lane; j < end; j += 64)
        m = fmaxf(m, __int_as_float(edata[j].y));
#pragma unroll
    for (int mask = 32; mask; mask >>= 1)
        m = fmaxf(m, __shfl_xor(m, mask, 64));

    // pass 2: 4 edges in flight, 16B/lane gathers
    float4 acc = make_float4(0.f, 0.f, 0.f, 0.f);
    float den = 0.f;
    for (int j0 = start; j0 < end; j0 += 4) {
        int j = j0 + slot;
        bool act = j < end;
        int2 ed = act ? edata[j] : make_int2(0, 0);
        float ee = act ? __expf(__int_as_float(ed.y) - m) : 0.f;
        float4 wv = *(const float4*)&Wh[(size_t)ed.x * OUT_F + fl * 4];
        den += ee;
        acc.x += ee * wv.x;
        acc.y += ee * wv.y;
        acc.z += ee * wv.z;
        acc.w += ee * wv.w;
    }
    // reduce across the 4 slots (lanes differing in bits 4,5)
#pragma unroll
    for (int mask = 16; mask <= 32; mask <<= 1) {
        acc.x += __shfl_xor(acc.x, mask, 64);
        acc.y += __shfl_xor(acc.y, mask, 64);
        acc.z += __shfl_xor(acc.z, mask, 64);
        acc.w += __shfl_xor(acc.w, mask, 64);
        den += __shfl_xor(den, mask, 64);
    }

    if (slot == 0) {
        float4 r;
        if (end > start) {
            float inv = 1.f / den;
            r.x = acc.x * inv; r.y = acc.y * inv;
            r.z = acc.z * inv; r.w = acc.w * inv;
            r.x = r.x > 0.f ? r.x : expm1f(r.x);
            r.y = r.y > 0.f ? r.y : expm1f(r.y);
            r.z = r.z > 0.f ? r.z : expm1f(r.z);
            r.w = r.w > 0.f ? r.w : expm1f(r.w);
        } else {
            r = make_float4(0.f, 0.f, 0.f, 0.f);
        }
        *(float4*)&out[(size_t)node * OUT_F + fl * 4] = r;
    }
}

extern "C" void kernel_launch(void* const* d_in, const int* in_sizes, int n_in,
                              void* d_out, int out_size, void* d_ws,
                              size_t ws_size, hipStream_t stream) {
    const float* h = (const float*)d_in[0];
    const int* ei = (const int*)d_in[1];
    const float* W = (const float*)d_in[2];
    const float* a = (const float*)d_in[3];
    float* out = (float*)d_out;

    float* ws = (float*)d_ws;
    float* Wh = ws;                                 // 3,200,000 floats
    float* e2 = ws + 3200000;                       // 50,000
    int* counts = (int*)(ws + 3250000);             // 50,000
    int* cursor = (int*)(ws + 3300000);             // 50,000
    int* off = (int*)(ws + 3350000);                // 50,001
    int2* edata = (int2*)(ws + 3410000);            // 800,000 int2 (6.4 MB)
    int* bsum = (int*)(ws + 5010000);               // 196

    // zero counts + cursor (contiguous)
    hipMemsetAsync(counts, 0, (size_t)100000 * 4, stream);

    k1_gemm<<<(N_NODES + 63) / 64, 256, 0, stream>>>(h, W, a, Wh, e2);
    k_hist<<<(N_EDGES + 255) / 256, 256, 0, stream>>>(ei, counts);
    k_scan1<<<SCAN_NB, 256, 0, stream>>>(counts, bsum);
    k_scan2<<<1, 256, 0, stream>>>(bsum);
    k_scan3<<<SCAN_NB, 256, 0, stream>>>(counts, bsum, off);
    k_scatter<<<(N_EDGES + 255) / 256, 256, 0, stream>>>(ei, e2, off, cursor,
                                                         edata);
    k_agg<<<(N_NODES * 64 + 255) / 256, 256, 0, stream>>>(off, edata, Wh, out);
}

// Round 5
// 101.909 us; speedup vs baseline: 3.0005x; 1.6245x over previous
//
#include <hip/hip_runtime.h>
#include <math.h>

#define N_NODES 50000
#define N_EDGES 800000
#define IN_F 256
#define OUT_F 64
#define ALPHA 0.2f

#define NPB 256                                   // nodes per bucket
#define NBKT ((N_NODES + NPB - 1) / NPB)          // 196 buckets
#define CAP 4608                                  // bucket capacity (mean 4096 + 8 sigma)
#define BIN_EPB 4096                              // edges per k_bin block
#define BIN_NB ((N_EDGES + BIN_EPB - 1) / BIN_EPB)  // 196

// K1: Wh = leaky_relu(h @ W); ew = exp(Wh @ a[64:128])  (no-max softmax)
__global__ __launch_bounds__(256) void k1_gemm(
    const float* __restrict__ h, const float* __restrict__ W,
    const float* __restrict__ a, float* __restrict__ Wh,
    float* __restrict__ ewout) {
    __shared__ float hs[64 * 68];
    __shared__ float wsm[64 * 64];

    const int tid = threadIdx.x;
    const int row0 = blockIdx.x * 64;
    const int cg = tid & 15;
    const int rg = tid >> 4;

    float acc[4][4] = {};

    for (int k0 = 0; k0 < IN_F; k0 += 64) {
        __syncthreads();
#pragma unroll
        for (int j = 0; j < 4; ++j) {
            int q = tid + j * 256;
            int r = q >> 4;
            int c4 = (q & 15) * 4;
            int row = row0 + r;
            float4 v = make_float4(0.f, 0.f, 0.f, 0.f);
            if (row < N_NODES)
                v = *(const float4*)&h[(size_t)row * IN_F + k0 + c4];
            *(float4*)&hs[r * 68 + c4] = v;
        }
#pragma unroll
        for (int j = 0; j < 4; ++j) {
            int q = tid + j * 256;
            int r = q >> 4;
            int c4 = (q & 15) * 4;
            *(float4*)&wsm[r * 64 + c4] =
                *(const float4*)&W[(size_t)(k0 + r) * OUT_F + c4];
        }
        __syncthreads();

        for (int kk = 0; kk < 64; ++kk) {
            float4 wv = *(const float4*)&wsm[kk * 64 + cg * 4];
#pragma unroll
            for (int i = 0; i < 4; ++i) {
                float hv = hs[(rg * 4 + i) * 68 + kk];
                acc[i][0] += hv * wv.x;
                acc[i][1] += hv * wv.y;
                acc[i][2] += hv * wv.z;
                acc[i][3] += hv * wv.w;
            }
        }
    }

    float a2[4];
#pragma unroll
    for (int j = 0; j < 4; ++j) a2[j] = a[OUT_F + cg * 4 + j];

#pragma unroll
    for (int i = 0; i < 4; ++i) {
        int row = row0 + rg * 4 + i;
        float4 lr;
        float p2 = 0.f;
        {
            float v;
            v = acc[i][0]; v = v > 0.f ? v : ALPHA * v; lr.x = v; p2 += v * a2[0];
            v = acc[i][1]; v = v > 0.f ? v : ALPHA * v; lr.y = v; p2 += v * a2[1];
            v = acc[i][2]; v = v > 0.f ? v : ALPHA * v; lr.z = v; p2 += v * a2[2];
            v = acc[i][3]; v = v > 0.f ? v : ALPHA * v; lr.w = v; p2 += v * a2[3];
        }
        if (row < N_NODES)
            *(float4*)&Wh[(size_t)row * OUT_F + cg * 4] = lr;
#pragma unroll
        for (int mask = 1; mask < 16; mask <<= 1)
            p2 += __shfl_xor(p2, mask, 64);
        if (cg == 0 && row < N_NODES) ewout[row] = __expf(p2);
    }
}

// init bucket cursors to bucket-region bases
__global__ __launch_bounds__(256) void k_init(int* __restrict__ gcursor) {
    int t = threadIdx.x;
    if (t < NBKT) gcursor[t] = t * CAP;
}

// pass 1: bin edges into NBKT bucket regions. Per-block LDS count -> one
// global atomic per (block,bucket) -> grouped (mostly-contiguous) writes.
// Payload packed: (src&255)<<16 | dst  (dst < 50000 < 65536)
__global__ __launch_bounds__(256) void k_bin(
    const int* __restrict__ ei, int* __restrict__ gcursor,
    int* __restrict__ binned) {
    __shared__ int bc[NBKT];
    const int t = threadIdx.x;
    if (t < NBKT) bc[t] = 0;
    __syncthreads();

    int s[16], d[16];
    const int e0 = blockIdx.x * BIN_EPB;
#pragma unroll
    for (int i = 0; i < 16; ++i) {
        int e = e0 + i * 256 + t;
        if (e < N_EDGES) {
            s[i] = ei[e];
            d[i] = ei[N_EDGES + e];
            atomicAdd(&bc[s[i] >> 8], 1);
        } else {
            s[i] = -1;
        }
    }
    __syncthreads();
    if (t < NBKT) {
        int cnt = bc[t];
        bc[t] = cnt ? atomicAdd(&gcursor[t], cnt) : 0;
    }
    __syncthreads();
#pragma unroll
    for (int i = 0; i < 16; ++i) {
        if (s[i] >= 0) {
            int bkt = s[i] >> 8;
            int idx = atomicAdd(&bc[bkt], 1);
            if (idx < (bkt + 1) * CAP)   // overflow guard (never triggers)
                binned[idx] = ((s[i] & 255) << 16) | d[i];
        }
    }
}

// pass 2: one block per bucket. LDS node-hist + scan (-> off), then place
// edges at exact CSR positions (writes land in the bucket's own ~13KB region).
__global__ __launch_bounds__(256) void k_order(
    const int* __restrict__ binned, const int* __restrict__ gcursor,
    int* __restrict__ off, int* __restrict__ sdF) {
    __shared__ int hist[NPB];
    __shared__ int sc[256];
    __shared__ int bbase_s;
    const int t = threadIdx.x;
    const int b = blockIdx.x;

    // bucket-count scan (every block does it; 196 L2-hit reads)
    int cntAll = 0;
    if (t < NBKT) {
        cntAll = gcursor[t] - t * CAP;
        if (cntAll > CAP) cntAll = CAP;
    }
    sc[t] = cntAll;
    hist[t] = 0;
    __syncthreads();
    for (int o = 1; o < 256; o <<= 1) {
        int u = (t >= o) ? sc[t - o] : 0;
        __syncthreads();
        sc[t] += u;
        __syncthreads();
    }
    if (t == 0) bbase_s = (b == 0) ? 0 : sc[b - 1];
    __syncthreads();
    const int bbase = bbase_s;
    const int cnt = (b == 0 && t == 0) ? 0 : 0;  // (placeholder, see below)
    int mycnt = gcursor[b] - b * CAP;
    if (mycnt > CAP) mycnt = CAP;
    const int rb = b * CAP;

    // node-level histogram
    for (int j = t; j < mycnt; j += 256)
        atomicAdd(&hist[binned[rb + j] >> 16], 1);
    __syncthreads();

    // exclusive scan of hist -> off
    int my = hist[t];
    sc[t] = my;
    __syncthreads();
    for (int o = 1; o < 256; o <<= 1) {
        int u = (t >= o) ? sc[t - o] : 0;
        __syncthreads();
        sc[t] += u;
        __syncthreads();
    }
    int basep = bbase + sc[t] - my;
    int node = b * NPB + t;
    if (node < N_NODES) off[node] = basep;
    if (b == 0 && t == 0) off[N_NODES] = N_EDGES;
    __syncthreads();
    hist[t] = basep;   // reuse as absolute cursor
    __syncthreads();

    // place
    for (int j = t; j < mycnt; j += 256) {
        int p = binned[rb + j];
        int pos = atomicAdd(&hist[p >> 16], 1);
        sdF[pos] = p & 0xFFFF;
    }
}

// K5: one wave per node; 4 edge-slots x 16 feature-lanes; no-max softmax.
__global__ __launch_bounds__(256) void k_agg(
    const int* __restrict__ off, const int* __restrict__ sdF,
    const float* __restrict__ ew, const float* __restrict__ Wh,
    float* __restrict__ out) {
    const int lane = threadIdx.x & 63;
    const int node = (blockIdx.x * blockDim.x + threadIdx.x) >> 6;
    if (node >= N_NODES) return;
    const int start = off[node];
    const int end = off[node + 1];
    const int slot = lane >> 4;
    const int fl = lane & 15;

    float4 acc = make_float4(0.f, 0.f, 0.f, 0.f);
    float den = 0.f;
    for (int j0 = start; j0 < end; j0 += 4) {
        int j = j0 + slot;
        bool act = j < end;
        int dd = act ? sdF[j] : 0;
        float w = act ? ew[dd] : 0.f;
        float4 wv = *(const float4*)&Wh[(size_t)dd * OUT_F + fl * 4];
        den += w;
        acc.x += w * wv.x;
        acc.y += w * wv.y;
        acc.z += w * wv.z;
        acc.w += w * wv.w;
    }
#pragma unroll
    for (int mask = 16; mask <= 32; mask <<= 1) {
        acc.x += __shfl_xor(acc.x, mask, 64);
        acc.y += __shfl_xor(acc.y, mask, 64);
        acc.z += __shfl_xor(acc.z, mask, 64);
        acc.w += __shfl_xor(acc.w, mask, 64);
        den += __shfl_xor(den, mask, 64);
    }

    if (slot == 0) {
        float4 r;
        if (end > start) {
            float inv = 1.f / den;
            r.x = acc.x * inv; r.y = acc.y * inv;
            r.z = acc.z * inv; r.w = acc.w * inv;
            r.x = r.x > 0.f ? r.x : expm1f(r.x);
            r.y = r.y > 0.f ? r.y : expm1f(r.y);
            r.z = r.z > 0.f ? r.z : expm1f(r.z);
            r.w = r.w > 0.f ? r.w : expm1f(r.w);
        } else {
            r = make_float4(0.f, 0.f, 0.f, 0.f);
        }
        *(float4*)&out[(size_t)node * OUT_F + fl * 4] = r;
    }
}

extern "C" void kernel_launch(void* const* d_in, const int* in_sizes, int n_in,
                              void* d_out, int out_size, void* d_ws,
                              size_t ws_size, hipStream_t stream) {
    const float* h = (const float*)d_in[0];
    const int* ei = (const int*)d_in[1];
    const float* W = (const float*)d_in[2];
    const float* a = (const float*)d_in[3];
    float* out = (float*)d_out;

    float* ws = (float*)d_ws;
    float* Wh = ws;                          // 3,200,000 f
    float* ew = ws + 3200000;                // 50,000 f
    int* gcursor = (int*)(ws + 3250000);     // 256
    int* off = (int*)(ws + 3250512);         // 50,001
    int* binned = (int*)(ws + 3301000);      // NBKT*CAP = 903,168
    int* sdF = (int*)(ws + 4205000);         // 800,000
    // end ~5,005,000 floats = 20.0 MB

    k_init<<<1, 256, 0, stream>>>(gcursor);
    k1_gemm<<<(N_NODES + 63) / 64, 256, 0, stream>>>(h, W, a, Wh, ew);
    k_bin<<<BIN_NB, 256, 0, stream>>>(ei, gcursor, binned);
    k_order<<<NBKT, 256, 0, stream>>>(binned, gcursor, off, sdF);
    k_agg<<<(N_NODES * 64 + 255) / 256, 256, 0, stream>>>(off, sdF, ew, Wh,
                                                          out);
}

// Round 6
// 89.509 us; speedup vs baseline: 3.4162x; 1.1385x over previous
//
#include <hip/hip_runtime.h>
#include <math.h>

#define N_NODES 50000
#define N_EDGES 800000
#define IN_F 256
#define OUT_F 64
#define ALPHA 0.2f

#define NPB 256
#define NBKT ((N_NODES + NPB - 1) / NPB)            // 196
#define CAP 4608
#define BIN_EPB 4096
#define BIN_NB ((N_EDGES + BIN_EPB - 1) / BIN_EPB)  // 196

typedef __attribute__((ext_vector_type(8))) short short8;
typedef __attribute__((ext_vector_type(4))) float f32x4;

__device__ __forceinline__ unsigned short f2b(float f) {
    unsigned u = __float_as_uint(f);
    unsigned r = (u + 0x7fffu + ((u >> 16) & 1u)) >> 16;  // RNE
    return (unsigned short)r;
}
__device__ __forceinline__ float b2f(unsigned short b) {
    return __uint_as_float(((unsigned)b) << 16);
}

// prep: W (f32, 256x64) -> Wfrag bf16 in per-lane MFMA B-fragment order.
// frag (s,t): k = s*32 + (l>>4)*8 + j, n = t*16 + (l&15); idx = ((s*4+t)*64+l)*8+j
__global__ __launch_bounds__(256) void k_wprep(const float* __restrict__ W,
                                               short* __restrict__ Wfrag) {
    int idx = blockIdx.x * 256 + threadIdx.x;  // 64 blocks -> 16384
    if (idx >= 8 * 4 * 64 * 8) return;
    int j = idx & 7;
    int l = (idx >> 3) & 63;
    int t = (idx >> 9) & 3;
    int s = idx >> 11;
    int k = s * 32 + (l >> 4) * 8 + j;
    int n = t * 16 + (l & 15);
    Wfrag[idx] = (short)f2b(W[k * OUT_F + n]);
}

// K1: Wh(bf16) = leaky_relu(h @ W); ew = exp(Wh @ a[64:128]).
// No LDS, no barriers. 4 waves/block, 32 rows/wave, B entirely in VGPRs.
__global__ __launch_bounds__(256, 2) void k1_mfma(
    const float* __restrict__ h, const short* __restrict__ Wfrag,
    const float* __restrict__ a, unsigned short* __restrict__ Whb,
    float* __restrict__ ew) {
    const int tid = threadIdx.x;
    const int wid = tid >> 6;
    const int l = tid & 63;
    const int lo = l & 15;
    const int g = l >> 4;
    const int m0 = (blockIdx.x * 4 + wid) * 32;

    // load all 32 B-fragments (entire W as bf16) into registers
    short8 b[8][4];
#pragma unroll
    for (int s = 0; s < 8; ++s)
#pragma unroll
        for (int t = 0; t < 4; ++t)
            b[s][t] = *(const short8*)&Wfrag[(((s * 4 + t) * 64) + l) * 8];

    const int r0 = m0 + lo;
    const int r1 = m0 + 16 + lo;
    const int r0c = r0 < N_NODES ? r0 : N_NODES - 1;
    const int r1c = r1 < N_NODES ? r1 : N_NODES - 1;

    f32x4 acc[2][4];
#pragma unroll
    for (int mt = 0; mt < 2; ++mt)
#pragma unroll
        for (int t = 0; t < 4; ++t)
            acc[mt][t] = (f32x4){0.f, 0.f, 0.f, 0.f};

#pragma unroll
    for (int s = 0; s < 8; ++s) {
        const float* p0 = &h[(size_t)r0c * IN_F + s * 32 + g * 8];
        const float* p1 = &h[(size_t)r1c * IN_F + s * 32 + g * 8];
        float4 x0 = *(const float4*)p0;
        float4 y0 = *(const float4*)(p0 + 4);
        float4 x1 = *(const float4*)p1;
        float4 y1 = *(const float4*)(p1 + 4);
        short8 A0, A1;
        A0[0] = (short)f2b(x0.x); A0[1] = (short)f2b(x0.y);
        A0[2] = (short)f2b(x0.z); A0[3] = (short)f2b(x0.w);
        A0[4] = (short)f2b(y0.x); A0[5] = (short)f2b(y0.y);
        A0[6] = (short)f2b(y0.z); A0[7] = (short)f2b(y0.w);
        A1[0] = (short)f2b(x1.x); A1[1] = (short)f2b(x1.y);
        A1[2] = (short)f2b(x1.z); A1[3] = (short)f2b(x1.w);
        A1[4] = (short)f2b(y1.x); A1[5] = (short)f2b(y1.y);
        A1[6] = (short)f2b(y1.z); A1[7] = (short)f2b(y1.w);
#pragma unroll
        for (int t = 0; t < 4; ++t) {
            acc[0][t] = __builtin_amdgcn_mfma_f32_16x16x32_bf16(
                A0, b[s][t], acc[0][t], 0, 0, 0);
            acc[1][t] = __builtin_amdgcn_mfma_f32_16x16x32_bf16(
                A1, b[s][t], acc[1][t], 0, 0, 0);
        }
    }

    float a2v[4];
#pragma unroll
    for (int t = 0; t < 4; ++t) a2v[t] = a[OUT_F + t * 16 + lo];

#pragma unroll
    for (int mt = 0; mt < 2; ++mt) {
        float p[4];
#pragma unroll
        for (int reg = 0; reg < 4; ++reg) {
            float pp = 0.f;
#pragma unroll
            for (int t = 0; t < 4; ++t) {
                float v = acc[mt][t][reg];
                v = v > 0.f ? v : ALPHA * v;
                acc[mt][t][reg] = v;
                pp += v * a2v[t];
            }
            p[reg] = pp;
        }
#pragma unroll
        for (int reg = 0; reg < 4; ++reg) {
#pragma unroll
            for (int mask = 1; mask < 16; mask <<= 1)
                p[reg] += __shfl_xor(p[reg], mask, 64);
        }
        const int rbase = m0 + mt * 16 + g * 4;
        if (lo == 0) {
#pragma unroll
            for (int reg = 0; reg < 4; ++reg)
                if (rbase + reg < N_NODES) ew[rbase + reg] = __expf(p[reg]);
        }
#pragma unroll
        for (int reg = 0; reg < 4; ++reg) {
            int r = rbase + reg;
            if (r < N_NODES) {
#pragma unroll
                for (int t = 0; t < 4; ++t)
                    Whb[(size_t)r * OUT_F + t * 16 + lo] =
                        f2b(acc[mt][t][reg]);
            }
        }
    }
}

__global__ __launch_bounds__(256) void k_init(int* __restrict__ gcursor) {
    int t = threadIdx.x;
    if (t < NBKT) gcursor[t] = t * CAP;
}

// pass 1: bin edges into bucket regions (src>>8), packed (src&255)<<16 | dst
__global__ __launch_bounds__(256) void k_bin(
    const int* __restrict__ ei, int* __restrict__ gcursor,
    int* __restrict__ binned) {
    __shared__ int bc[NBKT];
    const int t = threadIdx.x;
    if (t < NBKT) bc[t] = 0;
    __syncthreads();

    int s[16], d[16];
    const int e0 = blockIdx.x * BIN_EPB;
#pragma unroll
    for (int i = 0; i < 16; ++i) {
        int e = e0 + i * 256 + t;
        if (e < N_EDGES) {
            s[i] = ei[e];
            d[i] = ei[N_EDGES + e];
            atomicAdd(&bc[s[i] >> 8], 1);
        } else {
            s[i] = -1;
        }
    }
    __syncthreads();
    if (t < NBKT) {
        int cnt = bc[t];
        bc[t] = cnt ? atomicAdd(&gcursor[t], cnt) : 0;
    }
    __syncthreads();
#pragma unroll
    for (int i = 0; i < 16; ++i) {
        if (s[i] >= 0) {
            int bkt = s[i] >> 8;
            int idx = atomicAdd(&bc[bkt], 1);
            if (idx < (bkt + 1) * CAP)
                binned[idx] = ((s[i] & 255) << 16) | d[i];
        }
    }
}

// pass 2: per-bucket node hist + scan -> off; place edges in CSR order
__global__ __launch_bounds__(256) void k_order(
    const int* __restrict__ binned, const int* __restrict__ gcursor,
    int* __restrict__ off, int* __restrict__ sdF) {
    __shared__ int hist[NPB];
    __shared__ int sc[256];
    __shared__ int bbase_s;
    const int t = threadIdx.x;
    const int b = blockIdx.x;

    int cntAll = 0;
    if (t < NBKT) {
        cntAll = gcursor[t] - t * CAP;
        if (cntAll > CAP) cntAll = CAP;
    }
    sc[t] = cntAll;
    hist[t] = 0;
    __syncthreads();
    for (int o = 1; o < 256; o <<= 1) {
        int u = (t >= o) ? sc[t - o] : 0;
        __syncthreads();
        sc[t] += u;
        __syncthreads();
    }
    if (t == 0) bbase_s = (b == 0) ? 0 : sc[b - 1];
    __syncthreads();
    const int bbase = bbase_s;
    int mycnt = gcursor[b] - b * CAP;
    if (mycnt > CAP) mycnt = CAP;
    const int rb = b * CAP;

    for (int j = t; j < mycnt; j += 256)
        atomicAdd(&hist[binned[rb + j] >> 16], 1);
    __syncthreads();

    int my = hist[t];
    sc[t] = my;
    __syncthreads();
    for (int o = 1; o < 256; o <<= 1) {
        int u = (t >= o) ? sc[t - o] : 0;
        __syncthreads();
        sc[t] += u;
        __syncthreads();
    }
    int basep = bbase + sc[t] - my;
    int node = b * NPB + t;
    if (node < N_NODES) off[node] = basep;
    if (b == 0 && t == 0) off[N_NODES] = N_EDGES;
    __syncthreads();
    hist[t] = basep;
    __syncthreads();

    for (int j = t; j < mycnt; j += 256) {
        int p = binned[rb + j];
        int pos = atomicAdd(&hist[p >> 16], 1);
        sdF[pos] = p & 0xFFFF;
    }
}

// K5: one wave per node; 4 edge-slots x 16 feature-lanes; bf16 Wh gather.
__global__ __launch_bounds__(256) void k_agg(
    const int* __restrict__ off, const int* __restrict__ sdF,
    const float* __restrict__ ew, const unsigned short* __restrict__ Whb,
    float* __restrict__ out) {
    const int lane = threadIdx.x & 63;
    const int node = (blockIdx.x * blockDim.x + threadIdx.x) >> 6;
    if (node >= N_NODES) return;
    const int start = off[node];
    const int end = off[node + 1];
    const int slot = lane >> 4;
    const int fl = lane & 15;

    float4 acc = make_float4(0.f, 0.f, 0.f, 0.f);
    float den = 0.f;
    for (int j0 = start; j0 < end; j0 += 4) {
        int j = j0 + slot;
        bool act = j < end;
        int dd = act ? sdF[j] : 0;
        float w = act ? ew[dd] : 0.f;
        ushort4 wv = *(const ushort4*)&Whb[(size_t)dd * OUT_F + fl * 4];
        den += w;
        acc.x += w * b2f(wv.x);
        acc.y += w * b2f(wv.y);
        acc.z += w * b2f(wv.z);
        acc.w += w * b2f(wv.w);
    }
#pragma unroll
    for (int mask = 16; mask <= 32; mask <<= 1) {
        acc.x += __shfl_xor(acc.x, mask, 64);
        acc.y += __shfl_xor(acc.y, mask, 64);
        acc.z += __shfl_xor(acc.z, mask, 64);
        acc.w += __shfl_xor(acc.w, mask, 64);
        den += __shfl_xor(den, mask, 64);
    }

    if (slot == 0) {
        float4 r;
        if (end > start) {
            float inv = 1.f / den;
            r.x = acc.x * inv; r.y = acc.y * inv;
            r.z = acc.z * inv; r.w = acc.w * inv;
            r.x = r.x > 0.f ? r.x : expm1f(r.x);
            r.y = r.y > 0.f ? r.y : expm1f(r.y);
            r.z = r.z > 0.f ? r.z : expm1f(r.z);
            r.w = r.w > 0.f ? r.w : expm1f(r.w);
        } else {
            r = make_float4(0.f, 0.f, 0.f, 0.f);
        }
        *(float4*)&out[(size_t)node * OUT_F + fl * 4] = r;
    }
}

extern "C" void kernel_launch(void* const* d_in, const int* in_sizes, int n_in,
                              void* d_out, int out_size, void* d_ws,
                              size_t ws_size, hipStream_t stream) {
    const float* h = (const float*)d_in[0];
    const int* ei = (const int*)d_in[1];
    const float* W = (const float*)d_in[2];
    const float* a = (const float*)d_in[3];
    float* out = (float*)d_out;

    float* ws = (float*)d_ws;
    unsigned short* Whb = (unsigned short*)ws;   // 3.2M bf16 = 1.6M floats
    float* ew = ws + 1600000;                    // 50,000
    short* Wfrag = (short*)(ws + 1650000);       // 16,384 bf16 = 8192 floats
    int* gcursor = (int*)(ws + 1658192);         // 256
    int* off = (int*)(ws + 1658448);             // 50,001
    int* binned = (int*)(ws + 1708449);          // 903,168
    int* sdF = (int*)(ws + 2611617);             // 800,000  (ends 3.41M floats)

    k_init<<<1, 256, 0, stream>>>(gcursor);
    k_wprep<<<64, 256, 0, stream>>>(W, Wfrag);
    k1_mfma<<<(N_NODES + 127) / 128, 256, 0, stream>>>(h, Wfrag, a, Whb, ew);
    k_bin<<<BIN_NB, 256, 0, stream>>>(ei, gcursor, binned);
    k_order<<<NBKT, 256, 0, stream>>>(binned, gcursor, off, sdF);
    k_agg<<<(N_NODES * 64 + 255) / 256, 256, 0, stream>>>(off, sdF, ew, Whb,
                                                          out);
}

// Round 7
// 75.247 us; speedup vs baseline: 4.0637x; 1.1895x over previous
//
#include <hip/hip_runtime.h>
#include <math.h>

#define N_NODES 50000
#define N_EDGES 800000
#define IN_F 256
#define OUT_F 64
#define ALPHA 0.2f

#define NPB 256                 // nodes per bucket
#define NBKT 196                // ceil(50000/256)
#define CAP 4608                // bucket capacity (mean 4096 + 8 sigma)
#define BIN_EPB 4096
#define BIN_NB 196              // ceil(800000/4096)
#define GEMM_NB 391             // ceil(50000/128)

typedef __attribute__((ext_vector_type(8))) short short8;
typedef __attribute__((ext_vector_type(8))) unsigned short u16x8;
typedef __attribute__((ext_vector_type(4))) float f32x4;

__device__ __forceinline__ unsigned short f2b(float f) {
    unsigned u = __float_as_uint(f);
    unsigned r = (u + 0x7fffu + ((u >> 16) & 1u)) >> 16;  // RNE
    return (unsigned short)r;
}
__device__ __forceinline__ float b2f(unsigned short b) {
    return __uint_as_float(((unsigned)b) << 16);
}

// prep: W -> bf16 MFMA B-fragments; block 0 also inits gcursor.
__global__ __launch_bounds__(256) void k_wprep(const float* __restrict__ W,
                                               short* __restrict__ Wfrag,
                                               int* __restrict__ gcursor) {
    if (blockIdx.x == 0 && threadIdx.x < NBKT)
        gcursor[threadIdx.x] = threadIdx.x * CAP;
    int idx = blockIdx.x * 256 + threadIdx.x;  // 64 blocks -> 16384
    if (idx >= 8 * 4 * 64 * 8) return;
    int j = idx & 7;
    int l = (idx >> 3) & 63;
    int t = (idx >> 9) & 3;
    int s = idx >> 11;
    int k = s * 32 + (l >> 4) * 8 + j;
    int n = t * 16 + (l & 15);
    Wfrag[idx] = (short)f2b(W[k * OUT_F + n]);
}

// Fused: blocks [0,BIN_NB) bin edges into bucket regions;
//        blocks [BIN_NB, BIN_NB+GEMM_NB) do the MFMA GEMM.
__global__ __launch_bounds__(256, 2) void k_bc(
    const float* __restrict__ h, const short* __restrict__ Wfrag,
    const float* __restrict__ a, unsigned short* __restrict__ Whb,
    float* __restrict__ ew, const int* __restrict__ ei,
    int* __restrict__ gcursor, int* __restrict__ binned) {
    __shared__ int bc[NBKT];

    if (blockIdx.x < BIN_NB) {
        // ---- binning branch ----
        const int t = threadIdx.x;
        if (t < NBKT) bc[t] = 0;
        __syncthreads();

        int s[16], d[16];
        const int e0 = blockIdx.x * BIN_EPB;
#pragma unroll
        for (int i = 0; i < 16; ++i) {
            int e = e0 + i * 256 + t;
            if (e < N_EDGES) {
                s[i] = ei[e];
                d[i] = ei[N_EDGES + e];
                atomicAdd(&bc[s[i] >> 8], 1);
            } else {
                s[i] = -1;
            }
        }
        __syncthreads();
        if (t < NBKT) {
            int cnt = bc[t];
            bc[t] = cnt ? atomicAdd(&gcursor[t], cnt) : 0;
        }
        __syncthreads();
#pragma unroll
        for (int i = 0; i < 16; ++i) {
            if (s[i] >= 0) {
                int bkt = s[i] >> 8;
                int idx = atomicAdd(&bc[bkt], 1);
                if (idx < (bkt + 1) * CAP)
                    binned[idx] = ((s[i] & 255) << 16) | d[i];
            }
        }
        return;
    }

    // ---- GEMM branch: Wh(bf16) = leaky_relu(h@W); ew = exp(Wh@a2) ----
    const int bid = blockIdx.x - BIN_NB;
    const int tid = threadIdx.x;
    const int wid = tid >> 6;
    const int l = tid & 63;
    const int lo = l & 15;
    const int g = l >> 4;
    const int m0 = (bid * 4 + wid) * 32;

    short8 b[8][4];
#pragma unroll
    for (int s = 0; s < 8; ++s)
#pragma unroll
        for (int t = 0; t < 4; ++t)
            b[s][t] = *(const short8*)&Wfrag[(((s * 4 + t) * 64) + l) * 8];

    const int r0 = m0 + lo;
    const int r1 = m0 + 16 + lo;
    const int r0c = r0 < N_NODES ? r0 : N_NODES - 1;
    const int r1c = r1 < N_NODES ? r1 : N_NODES - 1;

    f32x4 acc[2][4];
#pragma unroll
    for (int mt = 0; mt < 2; ++mt)
#pragma unroll
        for (int t = 0; t < 4; ++t)
            acc[mt][t] = (f32x4){0.f, 0.f, 0.f, 0.f};

#pragma unroll
    for (int s = 0; s < 8; ++s) {
        const float* p0 = &h[(size_t)r0c * IN_F + s * 32 + g * 8];
        const float* p1 = &h[(size_t)r1c * IN_F + s * 32 + g * 8];
        float4 x0 = *(const float4*)p0;
        float4 y0 = *(const float4*)(p0 + 4);
        float4 x1 = *(const float4*)p1;
        float4 y1 = *(const float4*)(p1 + 4);
        short8 A0, A1;
        A0[0] = (short)f2b(x0.x); A0[1] = (short)f2b(x0.y);
        A0[2] = (short)f2b(x0.z); A0[3] = (short)f2b(x0.w);
        A0[4] = (short)f2b(y0.x); A0[5] = (short)f2b(y0.y);
        A0[6] = (short)f2b(y0.z); A0[7] = (short)f2b(y0.w);
        A1[0] = (short)f2b(x1.x); A1[1] = (short)f2b(x1.y);
        A1[2] = (short)f2b(x1.z); A1[3] = (short)f2b(x1.w);
        A1[4] = (short)f2b(y1.x); A1[5] = (short)f2b(y1.y);
        A1[6] = (short)f2b(y1.z); A1[7] = (short)f2b(y1.w);
#pragma unroll
        for (int t = 0; t < 4; ++t) {
            acc[0][t] = __builtin_amdgcn_mfma_f32_16x16x32_bf16(
                A0, b[s][t], acc[0][t], 0, 0, 0);
            acc[1][t] = __builtin_amdgcn_mfma_f32_16x16x32_bf16(
                A1, b[s][t], acc[1][t], 0, 0, 0);
        }
    }

    float a2v[4];
#pragma unroll
    for (int t = 0; t < 4; ++t) a2v[t] = a[OUT_F + t * 16 + lo];

#pragma unroll
    for (int mt = 0; mt < 2; ++mt) {
        float p[4];
#pragma unroll
        for (int reg = 0; reg < 4; ++reg) {
            float pp = 0.f;
#pragma unroll
            for (int t = 0; t < 4; ++t) {
                float v = acc[mt][t][reg];
                v = v > 0.f ? v : ALPHA * v;
                acc[mt][t][reg] = v;
                pp += v * a2v[t];
            }
            p[reg] = pp;
        }
#pragma unroll
        for (int reg = 0; reg < 4; ++reg) {
#pragma unroll
            for (int mask = 1; mask < 16; mask <<= 1)
                p[reg] += __shfl_xor(p[reg], mask, 64);
        }
        const int rbase = m0 + mt * 16 + g * 4;
        if (lo == 0) {
#pragma unroll
            for (int reg = 0; reg < 4; ++reg)
                if (rbase + reg < N_NODES) ew[rbase + reg] = __expf(p[reg]);
        }
#pragma unroll
        for (int reg = 0; reg < 4; ++reg) {
            int r = rbase + reg;
            if (r < N_NODES) {
#pragma unroll
                for (int t = 0; t < 4; ++t)
                    Whb[(size_t)r * OUT_F + t * 16 + lo] =
                        f2b(acc[mt][t][reg]);
            }
        }
    }
}

// Fused order+aggregate: one block per bucket. In-LDS node hist + scan +
// placement, then per-node softmax-aggregate + ELU, direct to out.
__global__ __launch_bounds__(1024) void k_fuse(
    const int* __restrict__ binned, const int* __restrict__ gcursor,
    const float* __restrict__ ew, const unsigned short* __restrict__ Whb,
    float* __restrict__ out) {
    __shared__ int lraw[CAP];
    __shared__ unsigned short ldst[CAP];
    __shared__ int hist[NPB];
    __shared__ int sstart[NPB];
    __shared__ int sc[NPB];
    const int t = threadIdx.x;
    const int b = blockIdx.x;

    int mycnt = gcursor[b] - b * CAP;
    mycnt = mycnt < 0 ? 0 : (mycnt > CAP ? CAP : mycnt);
    const int rb = b * CAP;

    if (t < NPB) hist[t] = 0;
    __syncthreads();
    for (int j = t; j < mycnt; j += 1024) {
        int p = binned[rb + j];
        lraw[j] = p;
        atomicAdd(&hist[p >> 16], 1);
    }
    __syncthreads();

    int my = 0;
    if (t < NPB) { my = hist[t]; sc[t] = my; }
    __syncthreads();
    for (int o = 1; o < NPB; o <<= 1) {
        int u = 0;
        if (t < NPB && t >= o) u = sc[t - o];
        __syncthreads();
        if (t < NPB) sc[t] += u;
        __syncthreads();
    }
    if (t < NPB) {
        sstart[t] = sc[t] - my;
        hist[t] = sc[t] - my;   // reuse as cursor
    }
    __syncthreads();

    for (int j = t; j < mycnt; j += 1024) {
        int p = lraw[j];
        int pos = atomicAdd(&hist[p >> 16], 1);
        ldst[pos] = (unsigned short)(p & 0xFFFF);
    }
    __syncthreads();

    // aggregate: 16 waves x 16 nodes; 8 edge-slots x 8 feature-lanes
    const int wave = t >> 6;
    const int lane = t & 63;
    const int slot = lane >> 3;
    const int fl = lane & 7;

    for (int ii = 0; ii < 16; ++ii) {
        const int i = wave * 16 + ii;
        const int node = b * NPB + i;
        if (node >= N_NODES) break;   // uniform per wave
        const int start = sstart[i];
        const int end = (i < NPB - 1) ? sstart[i + 1] : mycnt;

        float acc[8] = {0.f, 0.f, 0.f, 0.f, 0.f, 0.f, 0.f, 0.f};
        float den = 0.f;
        for (int j0 = start; j0 < end; j0 += 8) {
            int j = j0 + slot;
            bool act = j < end;
            int dd = act ? (int)ldst[j] : 0;
            float w = act ? ew[dd] : 0.f;
            u16x8 wv = *(const u16x8*)&Whb[(size_t)dd * OUT_F + fl * 8];
            den += w;
#pragma unroll
            for (int k = 0; k < 8; ++k) acc[k] += w * b2f(wv[k]);
        }
#pragma unroll
        for (int mask = 8; mask <= 32; mask <<= 1) {
#pragma unroll
            for (int k = 0; k < 8; ++k)
                acc[k] += __shfl_xor(acc[k], mask, 64);
            den += __shfl_xor(den, mask, 64);
        }

        if (slot == 0) {
            float4 r0, r1;
            if (end > start) {
                float inv = 1.f / den;
                float v;
                v = acc[0] * inv; r0.x = v > 0.f ? v : expm1f(v);
                v = acc[1] * inv; r0.y = v > 0.f ? v : expm1f(v);
                v = acc[2] * inv; r0.z = v > 0.f ? v : expm1f(v);
                v = acc[3] * inv; r0.w = v > 0.f ? v : expm1f(v);
                v = acc[4] * inv; r1.x = v > 0.f ? v : expm1f(v);
                v = acc[5] * inv; r1.y = v > 0.f ? v : expm1f(v);
                v = acc[6] * inv; r1.z = v > 0.f ? v : expm1f(v);
                v = acc[7] * inv; r1.w = v > 0.f ? v : expm1f(v);
            } else {
                r0 = make_float4(0.f, 0.f, 0.f, 0.f);
                r1 = r0;
            }
            *(float4*)&out[(size_t)node * OUT_F + fl * 8] = r0;
            *(float4*)&out[(size_t)node * OUT_F + fl * 8 + 4] = r1;
        }
    }
}

extern "C" void kernel_launch(void* const* d_in, const int* in_sizes, int n_in,
                              void* d_out, int out_size, void* d_ws,
                              size_t ws_size, hipStream_t stream) {
    const float* h = (const float*)d_in[0];
    const int* ei = (const int*)d_in[1];
    const float* W = (const float*)d_in[2];
    const float* a = (const float*)d_in[3];
    float* out = (float*)d_out;

    float* ws = (float*)d_ws;
    unsigned short* Whb = (unsigned short*)ws;   // 3.2M bf16 = 1.6M floats
    float* ew = ws + 1600000;                    // 50,000
    short* Wfrag = (short*)(ws + 1650000);       // 16,384 bf16
    int* gcursor = (int*)(ws + 1658192);         // 256
    int* binned = (int*)(ws + 1658448);          // NBKT*CAP = 903,168 ints

    k_wprep<<<64, 256, 0, stream>>>(W, Wfrag, gcursor);
    k_bc<<<BIN_NB + GEMM_NB, 256, 0, stream>>>(h, Wfrag, a, Whb, ew, ei,
                                               gcursor, binned);
    k_fuse<<<NBKT, 1024, 0, stream>>>(binned, gcursor, ew, Whb, out);
}

// Round 8
// 66.003 us; speedup vs baseline: 4.6329x; 1.1401x over previous
//
#include <hip/hip_runtime.h>
#include <math.h>

#define N_NODES 50000
#define N_EDGES 800000
#define IN_F 256
#define OUT_F 64
#define ALPHA 0.2f

#define NPB 128                 // nodes per bucket
#define NBKT 391                // ceil(50000/128)
#define CAP 2560                // bucket capacity (mean 2048 + ~11 sigma)
#define BIN_EPB 4096
#define BIN_NB 196              // ceil(800000/4096)
#define GEMM_NB 391             // ceil(50000/128)

typedef __attribute__((ext_vector_type(8))) short short8;
typedef __attribute__((ext_vector_type(8))) unsigned short u16x8;
typedef __attribute__((ext_vector_type(4))) float f32x4;

__device__ __forceinline__ unsigned short f2b(float f) {
    unsigned u = __float_as_uint(f);
    unsigned r = (u + 0x7fffu + ((u >> 16) & 1u)) >> 16;  // RNE
    return (unsigned short)r;
}
__device__ __forceinline__ float b2f(unsigned short b) {
    return __uint_as_float(((unsigned)b) << 16);
}

// prep: W -> bf16 MFMA B-fragments; also inits gcursor (NBKT entries).
__global__ __launch_bounds__(256) void k_wprep(const float* __restrict__ W,
                                               short* __restrict__ Wfrag,
                                               int* __restrict__ gcursor) {
    int idx = blockIdx.x * 256 + threadIdx.x;  // 64 blocks -> 16384
    if (idx < NBKT) gcursor[idx] = idx * CAP;
    if (idx >= 8 * 4 * 64 * 8) return;
    int j = idx & 7;
    int l = (idx >> 3) & 63;
    int t = (idx >> 9) & 3;
    int s = idx >> 11;
    int k = s * 32 + (l >> 4) * 8 + j;
    int n = t * 16 + (l & 15);
    Wfrag[idx] = (short)f2b(W[k * OUT_F + n]);
}

// Fused: blocks [0,BIN_NB) bin edges into bucket regions (src>>7);
//        blocks [BIN_NB, BIN_NB+GEMM_NB) do the MFMA GEMM.
__global__ __launch_bounds__(256, 2) void k_bc(
    const float* __restrict__ h, const short* __restrict__ Wfrag,
    const float* __restrict__ a, unsigned short* __restrict__ Whb,
    float* __restrict__ ew, const int* __restrict__ ei,
    int* __restrict__ gcursor, int* __restrict__ binned) {
    __shared__ int bc[NBKT];

    if (blockIdx.x < BIN_NB) {
        // ---- binning branch ----
        const int t = threadIdx.x;
        for (int i = t; i < NBKT; i += 256) bc[i] = 0;
        __syncthreads();

        int s[16], d[16];
        const int e0 = blockIdx.x * BIN_EPB;
#pragma unroll
        for (int i = 0; i < 16; ++i) {
            int e = e0 + i * 256 + t;
            if (e < N_EDGES) {
                s[i] = ei[e];
                d[i] = ei[N_EDGES + e];
                atomicAdd(&bc[s[i] >> 7], 1);
            } else {
                s[i] = -1;
            }
        }
        __syncthreads();
        for (int i = t; i < NBKT; i += 256) {
            int cnt = bc[i];
            bc[i] = cnt ? atomicAdd(&gcursor[i], cnt) : 0;
        }
        __syncthreads();
#pragma unroll
        for (int i = 0; i < 16; ++i) {
            if (s[i] >= 0) {
                int bkt = s[i] >> 7;
                int idx = atomicAdd(&bc[bkt], 1);
                if (idx < (bkt + 1) * CAP)
                    binned[idx] = ((s[i] & 127) << 16) | d[i];
            }
        }
        return;
    }

    // ---- GEMM branch: Wh(bf16) = leaky_relu(h@W); ew = exp(Wh@a2) ----
    const int bid = blockIdx.x - BIN_NB;
    const int tid = threadIdx.x;
    const int wid = tid >> 6;
    const int l = tid & 63;
    const int lo = l & 15;
    const int g = l >> 4;
    const int m0 = (bid * 4 + wid) * 32;

    short8 b[8][4];
#pragma unroll
    for (int s = 0; s < 8; ++s)
#pragma unroll
        for (int t = 0; t < 4; ++t)
            b[s][t] = *(const short8*)&Wfrag[(((s * 4 + t) * 64) + l) * 8];

    const int r0 = m0 + lo;
    const int r1 = m0 + 16 + lo;
    const int r0c = r0 < N_NODES ? r0 : N_NODES - 1;
    const int r1c = r1 < N_NODES ? r1 : N_NODES - 1;

    f32x4 acc[2][4];
#pragma unroll
    for (int mt = 0; mt < 2; ++mt)
#pragma unroll
        for (int t = 0; t < 4; ++t)
            acc[mt][t] = (f32x4){0.f, 0.f, 0.f, 0.f};

#pragma unroll
    for (int s = 0; s < 8; ++s) {
        const float* p0 = &h[(size_t)r0c * IN_F + s * 32 + g * 8];
        const float* p1 = &h[(size_t)r1c * IN_F + s * 32 + g * 8];
        float4 x0 = *(const float4*)p0;
        float4 y0 = *(const float4*)(p0 + 4);
        float4 x1 = *(const float4*)p1;
        float4 y1 = *(const float4*)(p1 + 4);
        short8 A0, A1;
        A0[0] = (short)f2b(x0.x); A0[1] = (short)f2b(x0.y);
        A0[2] = (short)f2b(x0.z); A0[3] = (short)f2b(x0.w);
        A0[4] = (short)f2b(y0.x); A0[5] = (short)f2b(y0.y);
        A0[6] = (short)f2b(y0.z); A0[7] = (short)f2b(y0.w);
        A1[0] = (short)f2b(x1.x); A1[1] = (short)f2b(x1.y);
        A1[2] = (short)f2b(x1.z); A1[3] = (short)f2b(x1.w);
        A1[4] = (short)f2b(y1.x); A1[5] = (short)f2b(y1.y);
        A1[6] = (short)f2b(y1.z); A1[7] = (short)f2b(y1.w);
#pragma unroll
        for (int t = 0; t < 4; ++t) {
            acc[0][t] = __builtin_amdgcn_mfma_f32_16x16x32_bf16(
                A0, b[s][t], acc[0][t], 0, 0, 0);
            acc[1][t] = __builtin_amdgcn_mfma_f32_16x16x32_bf16(
                A1, b[s][t], acc[1][t], 0, 0, 0);
        }
    }

    float a2v[4];
#pragma unroll
    for (int t = 0; t < 4; ++t) a2v[t] = a[OUT_F + t * 16 + lo];

#pragma unroll
    for (int mt = 0; mt < 2; ++mt) {
        float p[4];
#pragma unroll
        for (int reg = 0; reg < 4; ++reg) {
            float pp = 0.f;
#pragma unroll
            for (int t = 0; t < 4; ++t) {
                float v = acc[mt][t][reg];
                v = v > 0.f ? v : ALPHA * v;
                acc[mt][t][reg] = v;
                pp += v * a2v[t];
            }
            p[reg] = pp;
        }
#pragma unroll
        for (int reg = 0; reg < 4; ++reg) {
#pragma unroll
            for (int mask = 1; mask < 16; mask <<= 1)
                p[reg] += __shfl_xor(p[reg], mask, 64);
        }
        const int rbase = m0 + mt * 16 + g * 4;
        if (lo == 0) {
#pragma unroll
            for (int reg = 0; reg < 4; ++reg)
                if (rbase + reg < N_NODES) ew[rbase + reg] = __expf(p[reg]);
        }
#pragma unroll
        for (int reg = 0; reg < 4; ++reg) {
            int r = rbase + reg;
            if (r < N_NODES) {
#pragma unroll
                for (int t = 0; t < 4; ++t)
                    Whb[(size_t)r * OUT_F + t * 16 + lo] =
                        f2b(acc[mt][t][reg]);
            }
        }
    }
}

// Fused order+aggregate: one block per 128-node bucket. Edges reg-cached
// (<=3/thread), in-LDS hist+scan+placement, then per-node aggregate + ELU.
__global__ __launch_bounds__(1024) void k_fuse(
    const int* __restrict__ binned, const int* __restrict__ gcursor,
    const float* __restrict__ ew, const unsigned short* __restrict__ Whb,
    float* __restrict__ out) {
    __shared__ unsigned short ldst[CAP];
    __shared__ int hist[NPB];
    __shared__ int sstart[NPB];
    __shared__ int sc[NPB];
    const int t = threadIdx.x;
    const int b = blockIdx.x;

    int mycnt = gcursor[b] - b * CAP;
    mycnt = mycnt < 0 ? 0 : (mycnt > CAP ? CAP : mycnt);
    const int rb = b * CAP;

    if (t < NPB) hist[t] = 0;
    __syncthreads();

    // read edges into named registers (CAP <= 3*1024), histogram
    int p0 = -1, p1 = -1, p2 = -1;
    if (t < mycnt) {
        p0 = binned[rb + t];
        atomicAdd(&hist[p0 >> 16], 1);
    }
    if (t + 1024 < mycnt) {
        p1 = binned[rb + t + 1024];
        atomicAdd(&hist[p1 >> 16], 1);
    }
    if (t + 2048 < mycnt) {
        p2 = binned[rb + t + 2048];
        atomicAdd(&hist[p2 >> 16], 1);
    }
    __syncthreads();

    // exclusive scan over NPB=128 entries
    int my = 0;
    if (t < NPB) { my = hist[t]; sc[t] = my; }
    __syncthreads();
    for (int o = 1; o < NPB; o <<= 1) {
        int u = 0;
        if (t < NPB && t >= o) u = sc[t - o];
        __syncthreads();
        if (t < NPB) sc[t] += u;
        __syncthreads();
    }
    if (t < NPB) {
        sstart[t] = sc[t] - my;
        hist[t] = sc[t] - my;   // reuse as cursor
    }
    __syncthreads();

    // place
    if (p0 >= 0) ldst[atomicAdd(&hist[p0 >> 16], 1)] = (unsigned short)(p0 & 0xFFFF);
    if (p1 >= 0) ldst[atomicAdd(&hist[p1 >> 16], 1)] = (unsigned short)(p1 & 0xFFFF);
    if (p2 >= 0) ldst[atomicAdd(&hist[p2 >> 16], 1)] = (unsigned short)(p2 & 0xFFFF);
    __syncthreads();

    // aggregate: 16 waves x 8 nodes; 8 edge-slots x 8 feature-lanes
    const int wave = t >> 6;
    const int lane = t & 63;
    const int slot = lane >> 3;
    const int fl = lane & 7;

    for (int ii = 0; ii < 8; ++ii) {
        const int i = wave * 8 + ii;
        const int node = b * NPB + i;
        if (node >= N_NODES) break;   // wave-uniform
        const int start = sstart[i];
        const int end = (i < NPB - 1) ? sstart[i + 1] : mycnt;

        float acc[8] = {0.f, 0.f, 0.f, 0.f, 0.f, 0.f, 0.f, 0.f};
        float den = 0.f;
        for (int j0 = start; j0 < end; j0 += 8) {
            int j = j0 + slot;
            bool act = j < end;
            int dd = act ? (int)ldst[j] : 0;
            float w = act ? ew[dd] : 0.f;
            u16x8 wv = *(const u16x8*)&Whb[(size_t)dd * OUT_F + fl * 8];
            den += w;
#pragma unroll
            for (int k = 0; k < 8; ++k) acc[k] += w * b2f(wv[k]);
        }
#pragma unroll
        for (int mask = 8; mask <= 32; mask <<= 1) {
#pragma unroll
            for (int k = 0; k < 8; ++k)
                acc[k] += __shfl_xor(acc[k], mask, 64);
            den += __shfl_xor(den, mask, 64);
        }

        if (slot == 0) {
            float4 r0, r1;
            if (end > start) {
                float inv = 1.f / den;
                float v;
                v = acc[0] * inv; r0.x = v > 0.f ? v : expm1f(v);
                v = acc[1] * inv; r0.y = v > 0.f ? v : expm1f(v);
                v = acc[2] * inv; r0.z = v > 0.f ? v : expm1f(v);
                v = acc[3] * inv; r0.w = v > 0.f ? v : expm1f(v);
                v = acc[4] * inv; r1.x = v > 0.f ? v : expm1f(v);
                v = acc[5] * inv; r1.y = v > 0.f ? v : expm1f(v);
                v = acc[6] * inv; r1.z = v > 0.f ? v : expm1f(v);
                v = acc[7] * inv; r1.w = v > 0.f ? v : expm1f(v);
            } else {
                r0 = make_float4(0.f, 0.f, 0.f, 0.f);
                r1 = r0;
            }
            *(float4*)&out[(size_t)node * OUT_F + fl * 8] = r0;
            *(float4*)&out[(size_t)node * OUT_F + fl * 8 + 4] = r1;
        }
    }
}

extern "C" void kernel_launch(void* const* d_in, const int* in_sizes, int n_in,
                              void* d_out, int out_size, void* d_ws,
                              size_t ws_size, hipStream_t stream) {
    const float* h = (const float*)d_in[0];
    const int* ei = (const int*)d_in[1];
    const float* W = (const float*)d_in[2];
    const float* a = (const float*)d_in[3];
    float* out = (float*)d_out;

    float* ws = (float*)d_ws;
    unsigned short* Whb = (unsigned short*)ws;   // 3.2M bf16 = 1.6M floats
    float* ew = ws + 1600000;                    // 50,000
    short* Wfrag = (short*)(ws + 1650000);       // 16,384 bf16
    int* gcursor = (int*)(ws + 1658192);         // 512 (NBKT=391 used)
    int* binned = (int*)(ws + 1658704);          // NBKT*CAP = 1,000,960 ints

    k_wprep<<<64, 256, 0, stream>>>(W, Wfrag, gcursor);
    k_bc<<<BIN_NB + GEMM_NB, 256, 0, stream>>>(h, Wfrag, a, Whb, ew, ei,
                                               gcursor, binned);
    k_fuse<<<NBKT, 1024, 0, stream>>>(binned, gcursor, ew, Whb, out);
}